// Round 5
// baseline (457.080 us; speedup 1.0000x reference)
//
#include <hip/hip_runtime.h>
#include <hip/hip_bf16.h>
#include <cstdint>
#include <cstddef>

// Problem constants
#define BATCH 8
#define SEQN 4096
#define DIM 1024
#define KSLOT 128
#define MROWS (BATCH * SEQN)   // 32768
#define LN_EPS 1e-5f

typedef __hip_bfloat16 bf16;
typedef __attribute__((ext_vector_type(8))) short short8;   // 8 bf16 = 4 VGPRs (MFMA A/B frag)
typedef __attribute__((ext_vector_type(4))) float f32x4;    // MFMA C/D frag

// ---------- helpers ----------
__device__ __forceinline__ float bf2f(unsigned short u) {
    return __uint_as_float(((unsigned int)u) << 16);
}
__device__ __forceinline__ unsigned short f2bf(float f) {
    unsigned int u = __float_as_uint(f);
    unsigned int r = (u + 0x7fffu + ((u >> 16) & 1u)) >> 16;  // RNE
    return (unsigned short)r;
}
__device__ __forceinline__ float waveReduceSum(float v) {
    #pragma unroll
    for (int off = 32; off > 0; off >>= 1) v += __shfl_down(v, off, 64);
    return v;
}
__device__ __forceinline__ void load4(const float* p, float* o) {
    float4 v = *reinterpret_cast<const float4*>(p);
    o[0] = v.x; o[1] = v.y; o[2] = v.z; o[3] = v.w;
}
__device__ __forceinline__ void load4(const bf16* p, float* o) {
    ushort4 v = *reinterpret_cast<const ushort4*>(p);
    o[0] = bf2f(v.x); o[1] = bf2f(v.y); o[2] = bf2f(v.z); o[3] = bf2f(v.w);
}
__device__ __forceinline__ void store4(float* p, const float* o) {
    float4 v; v.x = o[0]; v.y = o[1]; v.z = o[2]; v.w = o[3];
    *reinterpret_cast<float4*>(p) = v;
}
__device__ __forceinline__ void store4(bf16* p, const float* o) {
    ushort4 v; v.x = f2bf(o[0]); v.y = f2bf(o[1]); v.z = f2bf(o[2]); v.w = f2bf(o[3]);
    *reinterpret_cast<ushort4*>(p) = v;
}

// async global->LDS, 16 B per lane (global_load_lds_dwordx4)
typedef __attribute__((address_space(1))) const void gvoid;
typedef __attribute__((address_space(3))) void lvoid;
__device__ __forceinline__ void async_cp16(const void* g, void* l) {
    __builtin_amdgcn_global_load_lds((gvoid*)g, (lvoid*)l, 16, 0, 0);
}

// ---------- fp32 SIMT NN GEMM partial (split-K over blockIdx.z=8) ----------
// P[z,k,d] = sum_{e in chunk z} A[k,e] * B[e,d]
__global__ __launch_bounds__(256) void nn_partial(
    const float* __restrict__ A, const float* __restrict__ B,
    float* __restrict__ P, int Ka, int E, int Db)
{
    __shared__ float As[16][68];
    __shared__ float Bs[16][68];
    int tid = threadIdx.x, tx = tid & 15, ty = tid >> 4;
    int k0 = blockIdx.x * 64, d0 = blockIdx.y * 64;
    int chunk = E >> 3, e0 = blockIdx.z * chunk;
    int lr = tid >> 2, lk = (tid & 3) * 4;     // A staging: row k0+lr, e off lk
    int er = tid >> 4, dc = (tid & 15) * 4;    // B staging: row e0+et+er, col d0+dc
    float acc[4][4] = {};
    for (int et = 0; et < chunk; et += 16) {
        float av[4], bv[4];
        load4(A + (size_t)(k0 + lr) * E + e0 + et + lk, av);
        load4(B + (size_t)(e0 + et + er) * Db + d0 + dc, bv);
        #pragma unroll
        for (int j = 0; j < 4; j++) { As[lk + j][lr] = av[j]; Bs[er][dc + j] = bv[j]; }
        __syncthreads();
        #pragma unroll
        for (int kk = 0; kk < 16; kk++) {
            float a_[4], b_[4];
            #pragma unroll
            for (int i = 0; i < 4; i++) { a_[i] = As[kk][ty * 4 + i]; b_[i] = Bs[kk][tx * 4 + i]; }
            #pragma unroll
            for (int i = 0; i < 4; i++)
                #pragma unroll
                for (int j = 0; j < 4; j++) acc[i][j] += a_[i] * b_[j];
        }
        __syncthreads();
    }
    float* base = P + ((size_t)blockIdx.z * Ka + k0) * Db + d0;
    #pragma unroll
    for (int i = 0; i < 4; i++) store4(base + (size_t)(ty * 4 + i) * Db + tx * 4, acc[i]);
}

// ---------- reduce 8 partials + split fp32 -> (hi, lo) bf16; both matrices ----------
__global__ __launch_bounds__(256) void reduce_split8(
    const float* __restrict__ P1, const float* __restrict__ P2,
    bf16* __restrict__ hi1, bf16* __restrict__ lo1,
    bf16* __restrict__ hi2, bf16* __restrict__ lo2, int n)
{
    int bid = blockIdx.x;
    const float* P; bf16 *hi, *lo; int base;
    if (bid < 128) { P = P1; hi = hi1; lo = lo1; base = bid; }
    else           { P = P2; hi = hi2; lo = lo2; base = bid - 128; }
    int i = (base * 256 + threadIdx.x) * 4;
    if (i >= n) return;
    float s[4] = {0.f, 0.f, 0.f, 0.f};
    #pragma unroll
    for (int z = 0; z < 8; z++) {
        float t[4];
        load4(P + (size_t)z * n + i, t);
        #pragma unroll
        for (int j = 0; j < 4; j++) s[j] += t[j];
    }
    ushort4 h, l;
    unsigned short hb[4], lb[4];
    #pragma unroll
    for (int j = 0; j < 4; j++) {
        hb[j] = f2bf(s[j]);
        lb[j] = f2bf(s[j] - bf2f(hb[j]));
    }
    h.x = hb[0]; h.y = hb[1]; h.z = hb[2]; h.w = hb[3];
    l.x = lb[0]; l.y = lb[1]; l.z = lb[2]; l.w = lb[3];
    reinterpret_cast<ushort4*>(hi)[i >> 2] = h;
    reinterpret_cast<ushort4*>(lo)[i >> 2] = l;
}

// ---------- bias0[k] = sum_e w0[k,e] * b_in[e] ----------
__global__ __launch_bounds__(64) void bias_comb(
    const float* __restrict__ w0, const float* __restrict__ b_in, float* __restrict__ bias0)
{
    int k = blockIdx.x, lane = threadIdx.x;
    float s = 0.0f;
    for (int e = lane; e < DIM; e += 64) s += w0[(size_t)k * DIM + e] * b_in[e];
    s = waveReduceSum(s);
    if (lane == 0) bias0[k] = s;
}

// ---------- input LayerNorm (fp32 in -> bf16 out) ----------
__global__ __launch_bounds__(256) void ln_in_kernel(
    const float* __restrict__ x, const float* __restrict__ g,
    const float* __restrict__ b, bf16* __restrict__ out)
{
    int r = blockIdx.x;
    int t = threadIdx.x;
    float v[4];
    load4(x + (size_t)r * DIM + t * 4, v);
    float sum = v[0] + v[1] + v[2] + v[3];
    float sq  = v[0]*v[0] + v[1]*v[1] + v[2]*v[2] + v[3]*v[3];
    sum = waveReduceSum(sum);
    sq  = waveReduceSum(sq);
    __shared__ float sA[4], sB[4];
    __shared__ float mean_s, rstd_s;
    int w = t >> 6;
    if ((t & 63) == 0) { sA[w] = sum; sB[w] = sq; }
    __syncthreads();
    if (t == 0) {
        float S = sA[0] + sA[1] + sA[2] + sA[3];
        float Q = sB[0] + sB[1] + sB[2] + sB[3];
        float mean = S * (1.0f / DIM);
        float var = Q * (1.0f / DIM) - mean * mean;
        mean_s = mean;
        rstd_s = rsqrtf(fmaxf(var, 0.0f) + LN_EPS);
    }
    __syncthreads();
    float mean = mean_s, rstd = rstd_s;
    float gv[4], bv[4], o[4];
    load4(g + t * 4, gv);
    load4(b + t * 4, bv);
    #pragma unroll
    for (int j = 0; j < 4; j++) o[j] = (v[j] - mean) * rstd * gv[j] + bv[j];
    store4(out + (size_t)r * DIM + t * 4, o);
}

// ---------- logits GEMM: 64x128 tile, split-B hi/lo, fp32 out ----------
// logits[m, k] = sum_d hln[m,d] * (Whi[k,d]+Wlo[k,d]) + bias0[k]
__global__ __launch_bounds__(256) void gemm_logits(
    const bf16* __restrict__ A, const bf16* __restrict__ Whi, const bf16* __restrict__ Wlo,
    const float* __restrict__ bias, float* __restrict__ C, int M, int Kin)
{
    __shared__ short As[64 * 32];    // 4 KB
    __shared__ short Wh[128 * 32];   // 8 KB
    __shared__ short Wl[128 * 32];   // 8 KB
    const int tid = threadIdx.x, wave = tid >> 6, lane = tid & 63;
    const int wm = wave >> 1, wn = wave & 1;           // wave: 32 rows x 64 cols
    const int m0 = blockIdx.x * 64;
    const int srow = tid >> 2, scol = (tid & 3) * 8;
    const bf16* aG  = A   + (size_t)(m0 + srow) * Kin + scol;
    const bf16* hG0 = Whi + (size_t)srow * Kin + scol;
    const bf16* hG1 = hG0 + (size_t)64 * Kin;
    const bf16* lG0 = Wlo + (size_t)srow * Kin + scol;
    const bf16* lG1 = lG0 + (size_t)64 * Kin;
    short* aL  = As + tid * 8;
    short* hL0 = Wh + tid * 8;  short* hL1 = Wh + 2048 + tid * 8;
    short* lL0 = Wl + tid * 8;  short* lL1 = Wl + 2048 + tid * 8;
    const int fr = lane & 15, kb = (lane >> 4) * 8;

    f32x4 acc[2][4];
    #pragma unroll
    for (int i = 0; i < 2; i++)
        #pragma unroll
        for (int j = 0; j < 4; j++) acc[i][j] = 0.0f;

    for (int kt = 0; kt < Kin; kt += 32) {
        async_cp16(aG + kt, aL);
        async_cp16(hG0 + kt, hL0);
        async_cp16(hG1 + kt, hL1);
        async_cp16(lG0 + kt, lL0);
        async_cp16(lG1 + kt, lL1);
        __syncthreads();
        short8 af[2], bh[4], bl[4];
        #pragma unroll
        for (int i = 0; i < 2; i++)
            af[i] = *(const short8*)(As + (wm * 32 + i * 16 + fr) * 32 + kb);
        #pragma unroll
        for (int j = 0; j < 4; j++) {
            bh[j] = *(const short8*)(Wh + (wn * 64 + j * 16 + fr) * 32 + kb);
            bl[j] = *(const short8*)(Wl + (wn * 64 + j * 16 + fr) * 32 + kb);
        }
        #pragma unroll
        for (int i = 0; i < 2; i++)
            #pragma unroll
            for (int j = 0; j < 4; j++) {
                acc[i][j] = __builtin_amdgcn_mfma_f32_16x16x32_bf16(af[i], bh[j], acc[i][j], 0, 0, 0);
                acc[i][j] = __builtin_amdgcn_mfma_f32_16x16x32_bf16(af[i], bl[j], acc[i][j], 0, 0, 0);
            }
        __syncthreads();
    }

    const int crow = (lane >> 4) * 4;   // C/D: col=lane&15, row=(lane>>4)*4+reg
    #pragma unroll
    for (int j = 0; j < 4; j++) {
        int col = wn * 64 + j * 16 + fr;
        float bv = bias[col];
        #pragma unroll
        for (int i = 0; i < 2; i++) {
            int rbase = m0 + wm * 32 + i * 16 + crow;
            #pragma unroll
            for (int r = 0; r < 4; r++)
                C[(size_t)(rbase + r) * KSLOT + col] = acc[i][j][r] + bv;
        }
    }
}

// ---------- softmax over N (axis=1): stage 1, partial online max/sum ----------
__global__ __launch_bounds__(256) void smax_part_kernel(
    const float* __restrict__ logits, float* __restrict__ pm, float* __restrict__ ps)
{
    int kb = blockIdx.x, nb = blockIdx.y, b = blockIdx.z;
    int tx = threadIdx.x, ty = threadIdx.y;
    int k = kb * 64 + tx;
    const float* base = logits + ((size_t)b * SEQN) * KSLOT + k;
    int n0 = nb * 256 + ty * 64;
    float m = -1e30f, s = 0.0f;
    for (int j = 0; j < 64; j++) {
        float v = base[(size_t)(n0 + j) * KSLOT];
        if (v > m) { s = s * __expf(m - v) + 1.0f; m = v; }
        else       { s += __expf(v - m); }
    }
    __shared__ float lm[4][64], ls[4][64];
    lm[ty][tx] = m; ls[ty][tx] = s;
    __syncthreads();
    if (ty == 0) {
        #pragma unroll
        for (int q = 1; q < 4; q++) {
            float m2 = lm[q][tx], s2 = ls[q][tx];
            float nm = fmaxf(m, m2);
            s = s * __expf(m - nm) + s2 * __expf(m2 - nm);
            m = nm;
        }
        int col = b * KSLOT + k;
        pm[col * 16 + nb] = m;
        ps[col * 16 + nb] = s;
    }
}

__global__ __launch_bounds__(256) void smax_comb_kernel(
    const float* __restrict__ pm, const float* __restrict__ ps,
    float* __restrict__ cm, float* __restrict__ cs)
{
    int c = blockIdx.x * 256 + threadIdx.x;  // 0..1023 = b*K+k
    float m = -1e30f, s = 0.0f;
    #pragma unroll
    for (int nb = 0; nb < 16; nb++) {
        float m2 = pm[c * 16 + nb], s2 = ps[c * 16 + nb];
        float nm = fmaxf(m, m2);
        s = s * __expf(m - nm) + s2 * __expf(m2 - nm);
        m = nm;
    }
    cm[c] = m;
    cs[c] = s;
}

// ---------- fused tail: l1-norm -> h3 GEMM (32-row strip, full D) -> LN -> relu(+x) ----------
// Per block: rows [r0, r0+32), all 1024 output cols. 512 threads = 8 waves,
// wave w owns cols [w*128, w*128+128).
// MFMA operands are SWAPPED (w-frag first): acc[i][j] holds
//   d = cbase + j*16 + gq*4 + r  (4 CONSECUTIVE d per lane -> float4 epilogue)
//   m = i*16 + fr
// __launch_bounds__(512,4): cap total regs at 128 so 2 blocks/CU fit (was 136 -> 1 block/CU).
__global__ __launch_bounds__(512, 4) void h3_fused(
    const float* __restrict__ logits, const float* __restrict__ cm, const float* __restrict__ cs,
    const bf16* __restrict__ Whi, const bf16* __restrict__ Wlo,
    const float* __restrict__ x, const float* __restrict__ g, const float* __restrict__ bb,
    float* __restrict__ out)
{
    __shared__ short As[32 * 128];          // 8 KB, XOR-swizzled a-tile (bf16)
    __shared__ float redS[8][32];           // per-wave row partial sums
    __shared__ float redQ[8][32];           // per-wave row partial sumsq
    __shared__ float mrowM[32], mrowR[32];  // per-row mean / rstd

    const int tid  = threadIdx.x;
    const int wave = tid >> 6, lane = tid & 63;
    const int fr = lane & 15, gq = lane >> 4;        // gq in 0..3
    const int r0 = blockIdx.x * 32;
    const int bIdx = r0 >> 12;                        // batch index (SEQN=4096)

    // ---- phase 1: a[row,k] = softmax/L1 of logits -> LDS bf16 (swizzled) ----
    {
        int row = tid >> 4;               // 0..31
        int c0  = (tid & 15) * 8;         // 0..120
        const float* lp = logits + (size_t)(r0 + row) * KSLOT + c0;
        float v[8], cmv[8], csv[8];
        load4(lp, v);                 load4(lp + 4, v + 4);
        const float* cmp = cm + bIdx * KSLOT + c0;
        const float* csp = cs + bIdx * KSLOT + c0;
        load4(cmp, cmv);              load4(cmp + 4, cmv + 4);
        load4(csp, csv);              load4(csp + 4, csv + 4);
        float e[8], s = 0.0f;
        #pragma unroll
        for (int j = 0; j < 8; j++) { e[j] = __expf(v[j] - cmv[j]) / csv[j]; s += e[j]; }
        #pragma unroll
        for (int off = 1; off < 16; off <<= 1) s += __shfl_xor(s, off, 64);  // 16 lanes = 1 row
        float inv = 1.0f / (1e-9f + s);
        short8 pk;
        #pragma unroll
        for (int j = 0; j < 8; j++) pk[j] = (short)f2bf(e[j] * inv);
        int csw = c0 ^ ((row & 7) << 3);  // 16B-granular XOR swizzle (kills 16-way conflict)
        *(short8*)(As + row * 128 + csw) = pk;
    }
    __syncthreads();

    // ---- phase 2: h3[32 x 128(wave)] = a @ (Whi+Wlo)^T, B from global (L2-hot) ----
    const int cbase = wave * 128;
    const int kb = gq * 8;
    f32x4 acc[2][8];
    #pragma unroll
    for (int i = 0; i < 2; i++)
        #pragma unroll
        for (int j = 0; j < 8; j++) acc[i][j] = 0.0f;

    for (int kt = 0; kt < KSLOT; kt += 32) {
        short8 af[2];
        #pragma unroll
        for (int i = 0; i < 2; i++) {
            int row = i * 16 + fr;
            af[i] = *(const short8*)(As + row * 128 + ((kt + kb) ^ ((row & 7) << 3)));
        }
        // 4 chunks of 2 d-tiles: only 16 B-frag VGPRs live at a time (reg cap 128)
        #pragma unroll
        for (int jc = 0; jc < 4; jc++) {
            short8 bh[2], bl[2];
            #pragma unroll
            for (int j = 0; j < 2; j++) {
                int d = cbase + (jc * 2 + j) * 16 + fr;
                bh[j] = *(const short8*)((const short*)Whi + (size_t)d * KSLOT + kt + kb);
                bl[j] = *(const short8*)((const short*)Wlo + (size_t)d * KSLOT + kt + kb);
            }
            #pragma unroll
            for (int j = 0; j < 2; j++)
                #pragma unroll
                for (int i = 0; i < 2; i++) {
                    // swapped operands: w-frag first -> d indexes C/D "row" (gq*4+r)
                    acc[i][jc * 2 + j] = __builtin_amdgcn_mfma_f32_16x16x32_bf16(bh[j], af[i], acc[i][jc * 2 + j], 0, 0, 0);
                    acc[i][jc * 2 + j] = __builtin_amdgcn_mfma_f32_16x16x32_bf16(bl[j], af[i], acc[i][jc * 2 + j], 0, 0, 0);
                }
        }
    }

    // ---- phase 3: per-row LN stats (h3 stays in fp32 regs) ----
    // acc[i][j][r]: m = i*16 + fr, d = cbase + j*16 + gq*4 + r
    {
        #pragma unroll
        for (int i = 0; i < 2; i++) {
            float s = 0.0f, q = 0.0f;
            #pragma unroll
            for (int j = 0; j < 8; j++)
                #pragma unroll
                for (int r = 0; r < 4; r++) {
                    float v = acc[i][j][r];
                    s += v; q += v * v;
                }
            // reduce across gq (lanes ^16, ^32 share the same m-row fr)
            s += __shfl_xor(s, 16, 64);  q += __shfl_xor(q, 16, 64);
            s += __shfl_xor(s, 32, 64);  q += __shfl_xor(q, 32, 64);
            if (gq == 0) { redS[wave][i * 16 + fr] = s; redQ[wave][i * 16 + fr] = q; }
        }
    }
    __syncthreads();
    if (tid < 32) {
        float S = 0.0f, Q = 0.0f;
        #pragma unroll
        for (int w = 0; w < 8; w++) { S += redS[w][tid]; Q += redQ[w][tid]; }
        float mean = S * (1.0f / DIM);
        float var  = Q * (1.0f / DIM) - mean * mean;
        mrowM[tid] = mean;
        mrowR[tid] = rsqrtf(fmaxf(var, 0.0f) + LN_EPS);
    }
    __syncthreads();

    // ---- phase 4: out = relu(LN(h3)*g + b + x), all float4 ----
    {
        #pragma unroll
        for (int i = 0; i < 2; i++) {
            int row = i * 16 + fr;
            float mean = mrowM[row], rstd = mrowR[row];
            const float* xr = x   + (size_t)(r0 + row) * DIM;
            float*       orow = out + (size_t)(r0 + row) * DIM;
            #pragma unroll
            for (int j = 0; j < 8; j++) {
                int d = cbase + j * 16 + gq * 4;
                float gv[4], bv[4], xv[4], o[4];
                load4(g + d, gv);
                load4(bb + d, bv);
                load4(xr + d, xv);
                #pragma unroll
                for (int r = 0; r < 4; r++) {
                    float z = (acc[i][j][r] - mean) * rstd * gv[r] + bv[r] + xv[r];
                    o[r] = fmaxf(z, 0.0f);
                }
                store4(orow + d, o);
            }
        }
    }
}

extern "C" void kernel_launch(void* const* d_in, const int* in_sizes, int n_in,
                              void* d_out, int out_size, void* d_ws, size_t ws_size,
                              hipStream_t stream)
{
    const float* x     = (const float*)d_in[0];
    const float* ln_g  = (const float*)d_in[1];
    const float* ln_b  = (const float*)d_in[2];
    const float* w_in  = (const float*)d_in[3];
    const float* b_in  = (const float*)d_in[4];
    const float* w0    = (const float*)d_in[5];
    const float* w1    = (const float*)d_in[6];
    const float* w_out = (const float*)d_in[7];
    const float* oln_g = (const float*)d_in[8];
    const float* oln_b = (const float*)d_in[9];
    float* out = (float*)d_out;   // final fp32 output only

    // ws layout:
    //   [0, 64 MiB)   hln bf16 (dead after logits GEMM)
    //   [64, 80 MiB)  P1 [64,68) + P2 [68,72) (dead after reduce), then logits fp32
    //   [80 MiB, ..)  wc_hi/wc_lo/wc2_hi/wc2_lo/bias0/softmax stats
    char* ws = (char*)d_ws;
    bf16*  hln    = (bf16*)ws;
    float* logits = (float*)(ws + 67108864);
    float* P1     = (float*)(ws + 67108864);            // 8x128x1024 fp32 = 4 MiB
    float* P2     = (float*)(ws + 71303168);            // 8x1024x128 fp32 = 4 MiB
    bf16*  wc_hi  = (bf16*)(ws + 83886080);             // 128x1024
    bf16*  wc_lo  = (bf16*)(ws + 84148224);
    bf16*  wc2_hi = (bf16*)(ws + 84410368);             // 1024x128
    bf16*  wc2_lo = (bf16*)(ws + 84672512);
    float* bias0  = (float*)(ws + 84934656);            // 128 f
    float* pm     = (float*)(ws + 84935168);            // 16384 f
    float* psum   = (float*)(ws + 85000704);            // 16384 f
    float* cm     = (float*)(ws + 85066240);            // 1024 f
    float* cs     = (float*)(ws + 85070336);            // 1024 f

    // 0a. w_comb = w0 @ w_in   (128x1024), split-K 8
    nn_partial<<<dim3(2, 16, 8), dim3(256), 0, stream>>>(w0, w_in, P1, KSLOT, DIM, DIM);
    // 0b. w_comb2 = w_out @ w1 (1024x128), split-K 8
    nn_partial<<<dim3(16, 2, 8), dim3(256), 0, stream>>>(w_out, w1, P2, DIM, DIM, KSLOT);
    // 0c. reduce partials + split hi/lo (both matrices, one launch)
    reduce_split8<<<dim3(256), dim3(256), 0, stream>>>(P1, P2, wc_hi, wc_lo, wc2_hi, wc2_lo, KSLOT * DIM);
    // 0d. bias0 = w0 @ b_in
    bias_comb<<<dim3(KSLOT), dim3(64), 0, stream>>>(w0, b_in, bias0);
    // 1. hln = LayerNorm(x)  (fp32 -> bf16)
    ln_in_kernel<<<dim3(MROWS), dim3(256), 0, stream>>>(x, ln_g, ln_b, hln);
    // 2. logits = hln @ w_comb^T + bias0   (64x128 tiles)
    gemm_logits<<<dim3(MROWS / 64), dim3(256), 0, stream>>>(
        hln, wc_hi, wc_lo, bias0, logits, MROWS, DIM);
    // 3-4. column softmax stats over N
    smax_part_kernel<<<dim3(KSLOT / 64, 16, BATCH), dim3(64, 4), 0, stream>>>(logits, pm, psum);
    smax_comb_kernel<<<dim3(4), dim3(256), 0, stream>>>(pm, psum, cm, cs);
    // 5-7. fused: a = L1(softmax(logits)); h3 = a @ w_comb2^T (fp32 regs);
    //       out = relu(LN(h3)*g+b + x). h3/a never touch HBM.
    h3_fused<<<dim3(MROWS / 32), dim3(512), 0, stream>>>(
        logits, cm, cs, wc2_hi, wc2_lo, x, oln_g, oln_b, out);
}

// Round 8
// 423.231 us; speedup vs baseline: 1.0800x; 1.0800x over previous
//
#include <hip/hip_runtime.h>
#include <hip/hip_bf16.h>
#include <cstdint>
#include <cstddef>

// Problem constants
#define BATCH 8
#define SEQN 4096
#define DIM 1024
#define KSLOT 128
#define MROWS (BATCH * SEQN)   // 32768
#define LN_EPS 1e-5f

typedef __hip_bfloat16 bf16;
typedef __attribute__((ext_vector_type(8))) short short8;   // 8 bf16 = 4 VGPRs (MFMA A/B frag)
typedef __attribute__((ext_vector_type(4))) float f32x4;    // MFMA C/D frag

// ---------- helpers ----------
__device__ __forceinline__ float bf2f(unsigned short u) {
    return __uint_as_float(((unsigned int)u) << 16);
}
__device__ __forceinline__ unsigned short f2bf(float f) {
    unsigned int u = __float_as_uint(f);
    unsigned int r = (u + 0x7fffu + ((u >> 16) & 1u)) >> 16;  // RNE
    return (unsigned short)r;
}
__device__ __forceinline__ float waveReduceSum(float v) {
    #pragma unroll
    for (int off = 32; off > 0; off >>= 1) v += __shfl_down(v, off, 64);
    return v;
}
__device__ __forceinline__ void load4(const float* p, float* o) {
    float4 v = *reinterpret_cast<const float4*>(p);
    o[0] = v.x; o[1] = v.y; o[2] = v.z; o[3] = v.w;
}
__device__ __forceinline__ void store4(float* p, const float* o) {
    float4 v; v.x = o[0]; v.y = o[1]; v.z = o[2]; v.w = o[3];
    *reinterpret_cast<float4*>(p) = v;
}

// async global->LDS, 16 B per lane (global_load_lds_dwordx4)
typedef __attribute__((address_space(1))) const void gvoid;
typedef __attribute__((address_space(3))) void lvoid;
__device__ __forceinline__ void async_cp16(const void* g, void* l) {
    __builtin_amdgcn_global_load_lds((gvoid*)g, (lvoid*)l, 16, 0, 0);
}

// ---------- fp32 SIMT NN GEMM partial (split-K over blockIdx.z=8) ----------
// P[z,k,d] = sum_{e in chunk z} A[k,e] * B[e,d]
__global__ __launch_bounds__(256) void nn_partial(
    const float* __restrict__ A, const float* __restrict__ B,
    float* __restrict__ P, int Ka, int E, int Db)
{
    __shared__ float As[16][68];
    __shared__ float Bs[16][68];
    int tid = threadIdx.x, tx = tid & 15, ty = tid >> 4;
    int k0 = blockIdx.x * 64, d0 = blockIdx.y * 64;
    int chunk = E >> 3, e0 = blockIdx.z * chunk;
    int lr = tid >> 2, lk = (tid & 3) * 4;     // A staging: row k0+lr, e off lk
    int er = tid >> 4, dc = (tid & 15) * 4;    // B staging: row e0+et+er, col d0+dc
    float acc[4][4] = {};
    for (int et = 0; et < chunk; et += 16) {
        float av[4], bv[4];
        load4(A + (size_t)(k0 + lr) * E + e0 + et + lk, av);
        load4(B + (size_t)(e0 + et + er) * Db + d0 + dc, bv);
        #pragma unroll
        for (int j = 0; j < 4; j++) { As[lk + j][lr] = av[j]; Bs[er][dc + j] = bv[j]; }
        __syncthreads();
        #pragma unroll
        for (int kk = 0; kk < 16; kk++) {
            float a_[4], b_[4];
            #pragma unroll
            for (int i = 0; i < 4; i++) { a_[i] = As[kk][ty * 4 + i]; b_[i] = Bs[kk][tx * 4 + i]; }
            #pragma unroll
            for (int i = 0; i < 4; i++)
                #pragma unroll
                for (int j = 0; j < 4; j++) acc[i][j] += a_[i] * b_[j];
        }
        __syncthreads();
    }
    float* base = P + ((size_t)blockIdx.z * Ka + k0) * Db + d0;
    #pragma unroll
    for (int i = 0; i < 4; i++) store4(base + (size_t)(ty * 4 + i) * Db + tx * 4, acc[i]);
}

// ---------- w1 prep: wc = sum_z P1; wg = wc * ln_g; split hi/lo; u = sum_d wg; v = sum_d wc*ln_b ----------
// one block per k (128 blocks x 256 thr)
__global__ __launch_bounds__(256) void w1_prep(
    const float* __restrict__ P1, const float* __restrict__ g, const float* __restrict__ lb,
    bf16* __restrict__ hi, bf16* __restrict__ lo,
    float* __restrict__ u, float* __restrict__ v)
{
    int k = blockIdx.x, tid = threadIdx.x;
    int d = tid * 4;
    float wcf[4] = {0.f, 0.f, 0.f, 0.f};
    #pragma unroll
    for (int z = 0; z < 8; z++) {
        float t[4];
        load4(P1 + ((size_t)z * KSLOT + k) * DIM + d, t);
        #pragma unroll
        for (int j = 0; j < 4; j++) wcf[j] += t[j];
    }
    float gv[4], bv[4];
    load4(g + d, gv);
    load4(lb + d, bv);
    float su = 0.f, sv = 0.f;
    ushort4 h, l;
    unsigned short hb[4], lbv[4];
    #pragma unroll
    for (int j = 0; j < 4; j++) {
        float wg = wcf[j] * gv[j];
        hb[j] = f2bf(wg);
        lbv[j] = f2bf(wg - bf2f(hb[j]));
        su += wg;
        sv += wcf[j] * bv[j];
    }
    h.x = hb[0]; h.y = hb[1]; h.z = hb[2]; h.w = hb[3];
    l.x = lbv[0]; l.y = lbv[1]; l.z = lbv[2]; l.w = lbv[3];
    reinterpret_cast<ushort4*>(hi)[((size_t)k * DIM + d) >> 2] = h;
    reinterpret_cast<ushort4*>(lo)[((size_t)k * DIM + d) >> 2] = l;
    su = waveReduceSum(su);
    sv = waveReduceSum(sv);
    __shared__ float sU[4], sV[4];
    int w = tid >> 6;
    if ((tid & 63) == 0) { sU[w] = su; sV[w] = sv; }
    __syncthreads();
    if (tid == 0) {
        u[k] = sU[0] + sU[1] + sU[2] + sU[3];
        v[k] = sV[0] + sV[1] + sV[2] + sV[3];
    }
}

// ---------- w2 split: reduce 8 partials of P2 -> hi/lo bf16 ----------
__global__ __launch_bounds__(256) void w2_split(
    const float* __restrict__ P, bf16* __restrict__ hi, bf16* __restrict__ lo, int n)
{
    int i = (blockIdx.x * 256 + threadIdx.x) * 4;
    if (i >= n) return;
    float s[4] = {0.f, 0.f, 0.f, 0.f};
    #pragma unroll
    for (int z = 0; z < 8; z++) {
        float t[4];
        load4(P + (size_t)z * n + i, t);
        #pragma unroll
        for (int j = 0; j < 4; j++) s[j] += t[j];
    }
    ushort4 h, l;
    unsigned short hb[4], lb[4];
    #pragma unroll
    for (int j = 0; j < 4; j++) {
        hb[j] = f2bf(s[j]);
        lb[j] = f2bf(s[j] - bf2f(hb[j]));
    }
    h.x = hb[0]; h.y = hb[1]; h.z = hb[2]; h.w = hb[3];
    l.x = lb[0]; l.y = lb[1]; l.z = lb[2]; l.w = lb[3];
    reinterpret_cast<ushort4*>(hi)[i >> 2] = h;
    reinterpret_cast<ushort4*>(lo)[i >> 2] = l;
}

// ---------- bias0[k] = sum_e w0[k,e] * b_in[e] ----------
__global__ __launch_bounds__(64) void bias_comb(
    const float* __restrict__ w0, const float* __restrict__ b_in, float* __restrict__ bias0)
{
    int k = blockIdx.x, lane = threadIdx.x;
    float s = 0.0f;
    for (int e = lane; e < DIM; e += 64) s += w0[(size_t)k * DIM + e] * b_in[e];
    s = waveReduceSum(s);
    if (lane == 0) bias0[k] = s;
}

// ---------- fused LN + logits GEMM ----------
// logits[m,k] = rstd_m * (x_bf16 @ wg^T)[m,k] - rstd_m*mean_m*u[k] + v[k] + bias0[k]
// Row stats (mean, rstd) computed from the fp32 x values during A-staging.
__global__ __launch_bounds__(256) void gemm_logits_fused(
    const float* __restrict__ x, const bf16* __restrict__ Whi, const bf16* __restrict__ Wlo,
    const float* __restrict__ u, const float* __restrict__ v, const float* __restrict__ bias0,
    float* __restrict__ C)
{
    __shared__ short As[64 * 32];    // 4 KB
    __shared__ short Wh[128 * 32];   // 8 KB
    __shared__ short Wl[128 * 32];   // 8 KB
    __shared__ float rowM[64], rowR[64];
    const int tid = threadIdx.x, wave = tid >> 6, lane = tid & 63;
    const int wm = wave >> 1, wn = wave & 1;           // wave: 32 rows x 64 cols
    const int m0 = blockIdx.x * 64;
    const int srow = tid >> 2, scol = (tid & 3) * 8;
    const bf16* hG0 = Whi + (size_t)srow * DIM + scol;
    const bf16* hG1 = hG0 + (size_t)64 * DIM;
    const bf16* lG0 = Wlo + (size_t)srow * DIM + scol;
    const bf16* lG1 = lG0 + (size_t)64 * DIM;
    short* hL0 = Wh + tid * 8;  short* hL1 = Wh + 2048 + tid * 8;
    short* lL0 = Wl + tid * 8;  short* lL1 = Wl + 2048 + tid * 8;
    const float* xG = x + (size_t)(m0 + srow) * DIM + scol;
    const int fr = lane & 15, kb = (lane >> 4) * 8;

    f32x4 acc[2][4];
    #pragma unroll
    for (int i = 0; i < 2; i++)
        #pragma unroll
        for (int j = 0; j < 4; j++) acc[i][j] = 0.0f;

    float s_acc = 0.0f, q_acc = 0.0f;

    for (int kt = 0; kt < DIM; kt += 32) {
        async_cp16(hG0 + kt, hL0);
        async_cp16(hG1 + kt, hL1);
        async_cp16(lG0 + kt, lL0);
        async_cp16(lG1 + kt, lL1);
        // A-staging: raw x fp32 -> bf16, accumulate row stats
        float xv[8];
        load4(xG + kt, xv);
        load4(xG + kt + 4, xv + 4);
        short8 pk;
        #pragma unroll
        for (int j = 0; j < 8; j++) {
            pk[j] = (short)f2bf(xv[j]);
            s_acc += xv[j];
            q_acc += xv[j] * xv[j];
        }
        *(short8*)(As + srow * 32 + scol) = pk;
        __syncthreads();
        short8 af[2], bh[4], bl[4];
        #pragma unroll
        for (int i = 0; i < 2; i++)
            af[i] = *(const short8*)(As + (wm * 32 + i * 16 + fr) * 32 + kb);
        #pragma unroll
        for (int j = 0; j < 4; j++) {
            bh[j] = *(const short8*)(Wh + (wn * 64 + j * 16 + fr) * 32 + kb);
            bl[j] = *(const short8*)(Wl + (wn * 64 + j * 16 + fr) * 32 + kb);
        }
        #pragma unroll
        for (int i = 0; i < 2; i++)
            #pragma unroll
            for (int j = 0; j < 4; j++) {
                acc[i][j] = __builtin_amdgcn_mfma_f32_16x16x32_bf16(af[i], bh[j], acc[i][j], 0, 0, 0);
                acc[i][j] = __builtin_amdgcn_mfma_f32_16x16x32_bf16(af[i], bl[j], acc[i][j], 0, 0, 0);
            }
        __syncthreads();
    }

    // row stats: 4 threads per row (tid quads) hold disjoint quarters
    s_acc += __shfl_xor(s_acc, 1, 64);  q_acc += __shfl_xor(q_acc, 1, 64);
    s_acc += __shfl_xor(s_acc, 2, 64);  q_acc += __shfl_xor(q_acc, 2, 64);
    if ((tid & 3) == 0) {
        float mean = s_acc * (1.0f / DIM);
        float var  = q_acc * (1.0f / DIM) - mean * mean;
        rowM[srow] = mean;
        rowR[srow] = rsqrtf(fmaxf(var, 0.0f) + LN_EPS);
    }
    __syncthreads();

    const int crow = (lane >> 4) * 4;   // C/D: col=lane&15, row=(lane>>4)*4+reg
    #pragma unroll
    for (int j = 0; j < 4; j++) {
        int col = wn * 64 + j * 16 + fr;
        float uc = u[col];
        float vc = v[col] + bias0[col];
        #pragma unroll
        for (int i = 0; i < 2; i++) {
            int rl0 = wm * 32 + i * 16 + crow;
            #pragma unroll
            for (int r = 0; r < 4; r++) {
                int rl = rl0 + r;
                float rstd = rowR[rl], mean = rowM[rl];
                C[(size_t)(m0 + rl) * KSLOT + col] = rstd * acc[i][j][r] - rstd * mean * uc + vc;
            }
        }
    }
}

// ---------- softmax over N: coalesced partial stats (float4 row-major reads) ----------
// grid (16 nb, 8 b), 256 thr. Block covers 256 rows x all 128 k.
__global__ __launch_bounds__(256) void smax_part_c(
    const float* __restrict__ logits, float* __restrict__ pm, float* __restrict__ ps)
{
    int nb = blockIdx.x, b = blockIdx.y;
    int t = threadIdx.x;
    int kq = (t & 31) * 4, rg = t >> 5;          // 4 k-cols, row-group 0..7
    const float* base = logits + ((size_t)(b * SEQN + nb * 256 + rg)) * KSLOT + kq;
    float m[4] = {-1e30f, -1e30f, -1e30f, -1e30f};
    float s[4] = {0.f, 0.f, 0.f, 0.f};
    for (int it = 0; it < 32; it++) {
        float vv[4];
        load4(base + (size_t)it * 8 * KSLOT, vv);
        #pragma unroll
        for (int j = 0; j < 4; j++) {
            float vj = vv[j];
            if (vj > m[j]) { s[j] = s[j] * __expf(m[j] - vj) + 1.0f; m[j] = vj; }
            else           { s[j] += __expf(vj - m[j]); }
        }
    }
    __shared__ float lm[8][128], ls[8][128];     // 8 KB
    #pragma unroll
    for (int j = 0; j < 4; j++) { lm[rg][kq + j] = m[j]; ls[rg][kq + j] = s[j]; }
    __syncthreads();
    if (t < 128) {
        float M = -1e30f, S = 0.f;
        #pragma unroll
        for (int r2 = 0; r2 < 8; r2++) {
            float m2 = lm[r2][t], s2 = ls[r2][t];
            float nm = fmaxf(M, m2);
            S = S * __expf(M - nm) + s2 * __expf(m2 - nm);
            M = nm;
        }
        int col = b * KSLOT + t;
        pm[col * 16 + nb] = M;
        ps[col * 16 + nb] = S;
    }
}

__global__ __launch_bounds__(256) void smax_comb_kernel(
    const float* __restrict__ pm, const float* __restrict__ ps,
    float* __restrict__ cm, float* __restrict__ cs)
{
    int c = blockIdx.x * 256 + threadIdx.x;  // 0..1023 = b*K+k
    float m = -1e30f, s = 0.0f;
    #pragma unroll
    for (int nb = 0; nb < 16; nb++) {
        float m2 = pm[c * 16 + nb], s2 = ps[c * 16 + nb];
        float nm = fmaxf(m, m2);
        s = s * __expf(m - nm) + s2 * __expf(m2 - nm);
        m = nm;
    }
    cm[c] = m;
    cs[c] = s;
}

// ---------- fused tail: l1-norm -> h3 GEMM (32-row strip, full D) -> LN -> relu(+x) ----------
// Swapped MFMA operands (w-frag first): acc[i][j] holds
//   d = cbase + j*16 + gq*4 + r  (4 consecutive d per lane -> float4 epilogue)
//   m = i*16 + fr
// No min-waves cap (1 block/CU; round-5 showed 2 blocks/CU thrashes L3: +66 MB traffic).
__global__ __launch_bounds__(512) void h3_fused(
    const float* __restrict__ logits, const float* __restrict__ cm, const float* __restrict__ cs,
    const bf16* __restrict__ Whi, const bf16* __restrict__ Wlo,
    const float* __restrict__ x, const float* __restrict__ g, const float* __restrict__ bb,
    float* __restrict__ out)
{
    __shared__ short As[32 * 128];          // 8 KB, XOR-swizzled a-tile (bf16)
    __shared__ float redS[8][32];           // per-wave row partial sums
    __shared__ float redQ[8][32];           // per-wave row partial sumsq
    __shared__ float mrowM[32], mrowR[32];  // per-row mean / rstd

    const int tid  = threadIdx.x;
    const int wave = tid >> 6, lane = tid & 63;
    const int fr = lane & 15, gq = lane >> 4;        // gq in 0..3
    const int r0 = blockIdx.x * 32;
    const int bIdx = r0 >> 12;                        // batch index (SEQN=4096)

    // ---- phase 1: a[row,k] = softmax/L1 of logits -> LDS bf16 (swizzled) ----
    {
        int row = tid >> 4;               // 0..31
        int c0  = (tid & 15) * 8;         // 0..120
        const float* lp = logits + (size_t)(r0 + row) * KSLOT + c0;
        float v[8], cmv[8], csv[8];
        load4(lp, v);                 load4(lp + 4, v + 4);
        const float* cmp = cm + bIdx * KSLOT + c0;
        const float* csp = cs + bIdx * KSLOT + c0;
        load4(cmp, cmv);              load4(cmp + 4, cmv + 4);
        load4(csp, csv);              load4(csp + 4, csv + 4);
        float e[8], s = 0.0f;
        #pragma unroll
        for (int j = 0; j < 8; j++) { e[j] = __expf(v[j] - cmv[j]) / csv[j]; s += e[j]; }
        #pragma unroll
        for (int off = 1; off < 16; off <<= 1) s += __shfl_xor(s, off, 64);  // 16 lanes = 1 row
        float inv = 1.0f / (1e-9f + s);
        short8 pk;
        #pragma unroll
        for (int j = 0; j < 8; j++) pk[j] = (short)f2bf(e[j] * inv);
        int csw = c0 ^ ((row & 7) << 3);  // 16B-granular XOR swizzle (kills 16-way conflict)
        *(short8*)(As + row * 128 + csw) = pk;
    }
    __syncthreads();

    // ---- phase 2: h3[32 x 128(wave)] = a @ (Whi+Wlo)^T, B from global (L2-hot) ----
    const int cbase = wave * 128;
    const int kb = gq * 8;
    f32x4 acc[2][8];
    #pragma unroll
    for (int i = 0; i < 2; i++)
        #pragma unroll
        for (int j = 0; j < 8; j++) acc[i][j] = 0.0f;

    for (int kt = 0; kt < KSLOT; kt += 32) {
        short8 af[2];
        #pragma unroll
        for (int i = 0; i < 2; i++) {
            int row = i * 16 + fr;
            af[i] = *(const short8*)(As + row * 128 + ((kt + kb) ^ ((row & 7) << 3)));
        }
        #pragma unroll
        for (int jc = 0; jc < 2; jc++) {
            short8 bh[4], bl[4];
            #pragma unroll
            for (int j = 0; j < 4; j++) {
                int d = cbase + (jc * 4 + j) * 16 + fr;
                bh[j] = *(const short8*)((const short*)Whi + (size_t)d * KSLOT + kt + kb);
                bl[j] = *(const short8*)((const short*)Wlo + (size_t)d * KSLOT + kt + kb);
            }
            #pragma unroll
            for (int j = 0; j < 4; j++)
                #pragma unroll
                for (int i = 0; i < 2; i++) {
                    // swapped operands: w-frag first -> d indexes C/D "row" (gq*4+r)
                    acc[i][jc * 4 + j] = __builtin_amdgcn_mfma_f32_16x16x32_bf16(bh[j], af[i], acc[i][jc * 4 + j], 0, 0, 0);
                    acc[i][jc * 4 + j] = __builtin_amdgcn_mfma_f32_16x16x32_bf16(bl[j], af[i], acc[i][jc * 4 + j], 0, 0, 0);
                }
        }
    }

    // ---- phase 3: per-row LN stats (h3 stays in fp32 regs) ----
    // acc[i][j][r]: m = i*16 + fr, d = cbase + j*16 + gq*4 + r
    {
        #pragma unroll
        for (int i = 0; i < 2; i++) {
            float s = 0.0f, q = 0.0f;
            #pragma unroll
            for (int j = 0; j < 8; j++)
                #pragma unroll
                for (int r = 0; r < 4; r++) {
                    float v = acc[i][j][r];
                    s += v; q += v * v;
                }
            // reduce across gq (lanes ^16, ^32 share the same m-row fr)
            s += __shfl_xor(s, 16, 64);  q += __shfl_xor(q, 16, 64);
            s += __shfl_xor(s, 32, 64);  q += __shfl_xor(q, 32, 64);
            if (gq == 0) { redS[wave][i * 16 + fr] = s; redQ[wave][i * 16 + fr] = q; }
        }
    }
    __syncthreads();
    if (tid < 32) {
        float S = 0.0f, Q = 0.0f;
        #pragma unroll
        for (int w = 0; w < 8; w++) { S += redS[w][tid]; Q += redQ[w][tid]; }
        float mean = S * (1.0f / DIM);
        float var  = Q * (1.0f / DIM) - mean * mean;
        mrowM[tid] = mean;
        mrowR[tid] = rsqrtf(fmaxf(var, 0.0f) + LN_EPS);
    }
    __syncthreads();

    // ---- phase 4: out = relu(LN(h3)*g + b + x), all float4 ----
    {
        #pragma unroll
        for (int i = 0; i < 2; i++) {
            int row = i * 16 + fr;
            float mean = mrowM[row], rstd = mrowR[row];
            const float* xr = x   + (size_t)(r0 + row) * DIM;
            float*       orow = out + (size_t)(r0 + row) * DIM;
            #pragma unroll
            for (int j = 0; j < 8; j++) {
                int d = cbase + j * 16 + gq * 4;
                float gv[4], bv[4], xv[4], o[4];
                load4(g + d, gv);
                load4(bb + d, bv);
                load4(xr + d, xv);
                #pragma unroll
                for (int r = 0; r < 4; r++) {
                    float z = (acc[i][j][r] - mean) * rstd * gv[r] + bv[r] + xv[r];
                    o[r] = fmaxf(z, 0.0f);
                }
                store4(orow + d, o);
            }
        }
    }
}

extern "C" void kernel_launch(void* const* d_in, const int* in_sizes, int n_in,
                              void* d_out, int out_size, void* d_ws, size_t ws_size,
                              hipStream_t stream)
{
    const float* x     = (const float*)d_in[0];
    const float* ln_g  = (const float*)d_in[1];
    const float* ln_b  = (const float*)d_in[2];
    const float* w_in  = (const float*)d_in[3];
    const float* b_in  = (const float*)d_in[4];
    const float* w0    = (const float*)d_in[5];
    const float* w1    = (const float*)d_in[6];
    const float* w_out = (const float*)d_in[7];
    const float* oln_g = (const float*)d_in[8];
    const float* oln_b = (const float*)d_in[9];
    float* out = (float*)d_out;   // final fp32 output only

    // ws layout:
    //   [64, 80 MiB)  P1 [64,68) + P2 [68,72) (dead after w1_prep/w2_split), then logits fp32
    //   [80 MiB, ..)  wc_hi/wc_lo/wc2_hi/wc2_lo/bias0/softmax stats/u/v
    char* ws = (char*)d_ws;
    float* logits = (float*)(ws + 67108864);
    float* P1     = (float*)(ws + 67108864);            // 8x128x1024 fp32 = 4 MiB
    float* P2     = (float*)(ws + 71303168);            // 8x1024x128 fp32 = 4 MiB
    bf16*  wc_hi  = (bf16*)(ws + 83886080);             // 128x1024 (g folded in)
    bf16*  wc_lo  = (bf16*)(ws + 84148224);
    bf16*  wc2_hi = (bf16*)(ws + 84410368);             // 1024x128
    bf16*  wc2_lo = (bf16*)(ws + 84672512);
    float* bias0  = (float*)(ws + 84934656);            // 128 f
    float* pm     = (float*)(ws + 84935168);            // 16384 f
    float* psum   = (float*)(ws + 85000704);            // 16384 f
    float* cm     = (float*)(ws + 85066240);            // 1024 f
    float* cs     = (float*)(ws + 85070336);            // 1024 f
    float* uvec   = (float*)(ws + 85074432);            // 128 f
    float* vvec   = (float*)(ws + 85078528);            // 128 f

    // 0a. w_comb partials = w0 @ w_in  (128x1024), split-K 8
    nn_partial<<<dim3(2, 16, 8), dim3(256), 0, stream>>>(w0, w_in, P1, KSLOT, DIM, DIM);
    // 0b. w_comb2 partials = w_out @ w1 (1024x128), split-K 8
    nn_partial<<<dim3(16, 2, 8), dim3(256), 0, stream>>>(w_out, w1, P2, DIM, DIM, KSLOT);
    // 0c. bias0 = w0 @ b_in
    bias_comb<<<dim3(KSLOT), dim3(64), 0, stream>>>(w0, b_in, bias0);
    // 0d. w1: reduce + fold ln_g + hi/lo split + u,v vectors (LN folded into GEMM epilogue)
    w1_prep<<<dim3(KSLOT), dim3(256), 0, stream>>>(P1, ln_g, ln_b, wc_hi, wc_lo, uvec, vvec);
    // 0e. w2: reduce + hi/lo split
    w2_split<<<dim3(128), dim3(256), 0, stream>>>(P2, wc2_hi, wc2_lo, KSLOT * DIM);
    // 1+2. logits = LN(x) @ wc^T + bias0, LN folded (reads raw x; ln_in kernel eliminated)
    gemm_logits_fused<<<dim3(MROWS / 64), dim3(256), 0, stream>>>(
        x, wc_hi, wc_lo, uvec, vvec, bias0, logits);
    // 3-4. column softmax stats over N (coalesced float4 reads)
    smax_part_c<<<dim3(16, BATCH), dim3(256), 0, stream>>>(logits, pm, psum);
    smax_comb_kernel<<<dim3(4), dim3(256), 0, stream>>>(pm, psum, cm, cs);
    // 5-7. fused: a = L1(softmax(logits)); h3 = a @ w_comb2^T (fp32 regs);
    //       out = relu(LN(h3)*g+b + x). h3/a never touch HBM.
    h3_fused<<<dim3(MROWS / 32), dim3(512), 0, stream>>>(
        logits, cm, cs, wc2_hi, wc2_lo, x, oln_g, oln_b, out);
}